// Round 5
// baseline (181.000 us; speedup 1.0000x reference)
//
#include <hip/hip_runtime.h>
#include <math.h>

#define EPSF 1e-8f
#define LOG2E 1.44269504f

typedef short short8 __attribute__((ext_vector_type(8)));
typedef float floatx4 __attribute__((ext_vector_type(4)));

__device__ __forceinline__ unsigned short f2bf(float f) {
    unsigned u = __builtin_bit_cast(unsigned, f);
    unsigned r = (u + 0x7FFFu + ((u >> 16) & 1u)) >> 16;   // RNE
    return (unsigned short)r;
}
__device__ __forceinline__ float bf2f(unsigned short h) {
    return __builtin_bit_cast(float, ((unsigned)h) << 16);
}

// ---- Prep ----
// blocks 0..31: train -> interleaved bf16 hi/lo records (row = 4 segs x [hi8|lo8]),
//               (tnorm,resid) float2, fp64 stats partials.
// blocks 32.. : query norms qn.
__global__ __launch_bounds__(256) void prep_kernel(const float* __restrict__ x,
                                                   const float* __restrict__ train,
                                                   const float* __restrict__ resid,
                                                   int n, int m,
                                                   float2* __restrict__ tr2,
                                                   float* __restrict__ qn,
                                                   short* __restrict__ tb,
                                                   double* __restrict__ pS1,
                                                   double* __restrict__ pS2) {
    int tid = threadIdx.x;
    int b = blockIdx.x;
    if (b < 32) {
        __shared__ double s1s[256];
        __shared__ double s2s[256];
        int rowsPerBlock = n >> 5;          // 256
        int rbase = b * rowsPerBlock;
        for (int r = rbase + tid; r < rbase + rowsPerBlock; r += 256) {
            const float4* row = (const float4*)(train + (size_t)r * 32);
            float s = 0.f;
#pragma unroll
            for (int kb = 0; kb < 4; ++kb) {
                float4 f0 = row[kb * 2], f1 = row[kb * 2 + 1];
                float fv[8] = {f0.x, f0.y, f0.z, f0.w, f1.x, f1.y, f1.z, f1.w};
                short8 h, l;
#pragma unroll
                for (int j = 0; j < 8; ++j) {
                    unsigned short hb = f2bf(fv[j]);
                    h[j] = (short)hb;
                    l[j] = (short)f2bf(fv[j] - bf2f(hb));
                    s = fmaf(fv[j], fv[j], s);
                }
                // interleaved: row record = 64 shorts, seg kb at [kb*16 .. kb*16+15]
                *(short8*)(tb + (size_t)r * 64 + kb * 16) = h;
                *(short8*)(tb + (size_t)r * 64 + kb * 16 + 8) = l;
            }
            tr2[r] = make_float2(s, resid[r]);
        }
        // stats partials (column sums, fp64)
        int dim = tid & 31;
        int grp = tid >> 5;
        int rpt = rowsPerBlock >> 3;
        int r0 = rbase + grp * rpt;
        double s1 = 0.0, s2 = 0.0;
        for (int i = 0; i < rpt; ++i) {
            float v = train[(size_t)(r0 + i) * 32 + dim];
            s1 += (double)v;
            s2 += (double)v * (double)v;
        }
        s1s[tid] = s1;
        s2s[tid] = s2;
        __syncthreads();
        if (tid < 32) {
            double a = 0.0, c2 = 0.0;
            for (int g = 0; g < 8; ++g) { a += s1s[g * 32 + tid]; c2 += s2s[g * 32 + tid]; }
            pS1[b * 32 + tid] = a;
            pS2[b * 32 + tid] = c2;
        }
    } else {
        int r = (b - 32) * 256 + tid;
        if (r < m) {
            const float4* row = (const float4*)(x + (size_t)r * 32);
            float s = 0.f;
#pragma unroll
            for (int k = 0; k < 8; ++k) {
                float4 t = row[k];
                s = fmaf(t.x, t.x, s); s = fmaf(t.y, t.y, s);
                s = fmaf(t.z, t.z, s); s = fmaf(t.w, t.w, s);
            }
            qn[r] = s;
        }
    }
}

// ---- KDE via MFMA: 2-term bf16 split, M=32/wave, N-tiles of 16, K=32 per MFMA ----
__global__ __launch_bounds__(256, 8) void kde_kernel(const float* __restrict__ x,
                                                     const short* __restrict__ tb,
                                                     const float2* __restrict__ tr2,
                                                     const float* __restrict__ qn,
                                                     const double* __restrict__ pS1,
                                                     const double* __restrict__ pS2,
                                                     int m, int n, int nchunks,
                                                     float* __restrict__ numP,
                                                     float* __restrict__ denP) {
    __shared__ double sred[32];
    __shared__ float sC[2];   // negcl, C2
    int tid = threadIdx.x;

    // --- Scott's rule prologue (pS1/pS2 tiny, L2-hot) ---
    if (tid < 32) {
        double a = 0.0, b2 = 0.0;
        for (int k = 0; k < 32; ++k) { a += pS1[k * 32 + tid]; b2 += pS2[k * 32 + tid]; }
        double var = (b2 - a * a / (double)n) / (double)(n - 1);  // ddof=1
        sred[tid] = sqrt(var);
    }
    __syncthreads();
    if (tid == 0) {
        float ms = 0.f;
        for (int k = 0; k < 32; ++k) ms += (float)sred[k];
        ms *= (1.0f / 32.0f);
        float bw = ms * powf((float)n, -1.0f / 36.0f);
        float c = 1.0f / (2.0f * bw * bw);
        sC[0] = -c * LOG2E;        // negcl
        sC[1] = 2.0f * c * LOG2E;  // C2
    }
    __syncthreads();
    float negcl = sC[0], C2 = sC[1];

    int lane = tid & 63;
    int wave = tid >> 6;
    int col = lane & 15;      // A m-index / B n-index / D col
    int quad = lane >> 4;     // D rows = quad*4 + r
    int Mbase = blockIdx.x * 128 + wave * 32;
    int chunk = n / nchunks;
    int Nstart = blockIdx.y * chunk;
    int ntiles = chunk >> 4;

    // --- A fragments: queries -> bf16 hi/lo, register-resident ---
    short8 ah[2], al[2];
#pragma unroll
    for (int s = 0; s < 2; ++s) {
        const float* xp = x + (size_t)(Mbase + s * 16 + col) * 32 + quad * 8;
        float4 f0 = *(const float4*)xp;
        float4 f1 = *(const float4*)(xp + 4);
        float fv[8] = {f0.x, f0.y, f0.z, f0.w, f1.x, f1.y, f1.z, f1.w};
#pragma unroll
        for (int j = 0; j < 8; ++j) {
            unsigned short hb = f2bf(fv[j]);
            ah[s][j] = (short)hb;
            al[s][j] = (short)f2bf(fv[j] - bf2f(hb));
        }
    }

    // --- per-row log2-domain query-norm term ---
    float alpha[2][4];
#pragma unroll
    for (int s = 0; s < 2; ++s)
#pragma unroll
        for (int r = 0; r < 4; ++r)
            alpha[s][r] = negcl * qn[Mbase + s * 16 + quad * 4 + r];

    float num[2][4] = {{0.f, 0.f, 0.f, 0.f}, {0.f, 0.f, 0.f, 0.f}};
    float den[2][4] = {{0.f, 0.f, 0.f, 0.f}, {0.f, 0.f, 0.f, 0.f}};

    const short* tp = tb + (size_t)(Nstart + col) * 64 + quad * 16;
    const float2* trp = tr2 + Nstart + col;

    for (int it = 0; it < ntiles; ++it) {
        const short8 bh = *(const short8*)(tp);       // b128
        const short8 bl = *(const short8*)(tp + 8);   // b128, same base +16B
        float2 tv = *trp;                             // (tnorm, resid), one b64
        float beta = negcl * tv.x;
        float rv = tv.y;

#pragma unroll
        for (int s = 0; s < 2; ++s) {
            floatx4 acc = {0.f, 0.f, 0.f, 0.f};
            acc = __builtin_amdgcn_mfma_f32_16x16x32_bf16(ah[s], bh, acc, 0, 0, 0);
            acc = __builtin_amdgcn_mfma_f32_16x16x32_bf16(ah[s], bl, acc, 0, 0, 0);
            acc = __builtin_amdgcn_mfma_f32_16x16x32_bf16(al[s], bh, acc, 0, 0, 0);
#pragma unroll
            for (int r = 0; r < 4; ++r) {
                float arg = fminf(fmaf(C2, acc[r], alpha[s][r] + beta), 0.0f);
                float w = __builtin_amdgcn_exp2f(arg);   // raw v_exp_f32
                num[s][r] = fmaf(w, rv, num[s][r]);
                den[s][r] += w;
            }
        }
        tp += 16 * 64;
        trp += 16;
    }

    // --- reduce across the 16 lanes sharing each row set ---
#pragma unroll
    for (int s = 0; s < 2; ++s)
#pragma unroll
        for (int r = 0; r < 4; ++r) {
#pragma unroll
            for (int msk = 1; msk < 16; msk <<= 1) {
                num[s][r] += __shfl_xor(num[s][r], msk);
                den[s][r] += __shfl_xor(den[s][r], msk);
            }
        }
    if (col == 0) {
#pragma unroll
        for (int s = 0; s < 2; ++s)
#pragma unroll
            for (int r = 0; r < 4; ++r) {
                int q = Mbase + s * 16 + quad * 4 + r;
                numP[(size_t)blockIdx.y * m + q] = num[s][r];
                denP[(size_t)blockIdx.y * m + q] = den[s][r];
            }
    }
}

// ---- Fused reduce + combine (last-block-done pattern; counter pre-zeroed) ----
__global__ __launch_bounds__(256) void reduce_combine(const float* __restrict__ numP,
                                                      const float* __restrict__ denP,
                                                      const float* __restrict__ sigma,
                                                      float* __restrict__ rxbuf,
                                                      float* __restrict__ bred,
                                                      unsigned* __restrict__ counter,
                                                      float* __restrict__ out,
                                                      int m, int nchunks, int nb) {
    __shared__ float red[256];
    int tid = threadIdx.x;
    int q = blockIdx.x * 256 + tid;

    float num = 0.f, den = 0.f;
    for (int s = 0; s < nchunks; ++s) {
        num += numP[(size_t)s * m + q];
        den += denP[(size_t)s * m + q];
    }
    float rx = num / (den + EPSF);
    rxbuf[q] = rx;
    float sg = sigma[q];

    red[tid] = rx; __syncthreads();
    for (int o = 128; o > 0; o >>= 1) { if (tid < o) red[tid] = fminf(red[tid], red[tid + o]); __syncthreads(); }
    if (tid == 0) bred[0 * nb + blockIdx.x] = red[0];
    __syncthreads();
    red[tid] = rx; __syncthreads();
    for (int o = 128; o > 0; o >>= 1) { if (tid < o) red[tid] = fmaxf(red[tid], red[tid + o]); __syncthreads(); }
    if (tid == 0) bred[1 * nb + blockIdx.x] = red[0];
    __syncthreads();
    red[tid] = sg; __syncthreads();
    for (int o = 128; o > 0; o >>= 1) { if (tid < o) red[tid] = fminf(red[tid], red[tid + o]); __syncthreads(); }
    if (tid == 0) bred[2 * nb + blockIdx.x] = red[0];
    __syncthreads();
    red[tid] = sg; __syncthreads();
    for (int o = 128; o > 0; o >>= 1) { if (tid < o) red[tid] = fmaxf(red[tid], red[tid + o]); __syncthreads(); }
    if (tid == 0) bred[3 * nb + blockIdx.x] = red[0];

    // last block finishes: global extrema + output write
    __shared__ unsigned done;
    __threadfence();                       // release bred/rxbuf (device scope)
    __syncthreads();
    if (tid == 0) done = atomicAdd(counter, 1u);
    __syncthreads();
    if (done != (unsigned)(nb - 1)) return;
    __threadfence();                       // acquire other blocks' writes

    __shared__ float sc[4];
    if (tid < 64) {
        float v0 = (tid < nb) ? bred[0 * nb + tid] : INFINITY;
        float v1 = (tid < nb) ? bred[1 * nb + tid] : -INFINITY;
        float v2 = (tid < nb) ? bred[2 * nb + tid] : INFINITY;
        float v3 = (tid < nb) ? bred[3 * nb + tid] : -INFINITY;
        for (int o = 32; o > 0; o >>= 1) {
            v0 = fminf(v0, __shfl_xor(v0, o));
            v1 = fmaxf(v1, __shfl_xor(v1, o));
            v2 = fminf(v2, __shfl_xor(v2, o));
            v3 = fmaxf(v3, __shfl_xor(v3, o));
        }
        if (tid == 0) {
            sc[0] = v0;
            sc[1] = 1.0f / (v1 - v0 + EPSF);
            sc[2] = v2;
            sc[3] = 1.0f / (v3 - v2 + EPSF);
        }
    }
    __syncthreads();
    float rxmin = sc[0], invr = sc[1], smin = sc[2], invs = sc[3];
    for (int qq = tid; qq < m; qq += 256) {
        float t1 = 0.5f * (rxbuf[qq] - rxmin) * invr;
        float t2 = 0.5f * (sigma[qq] - smin) * invs;
        out[qq] = t1 + t2;
    }
}

extern "C" void kernel_launch(void* const* d_in, const int* in_sizes, int n_in,
                              void* d_out, int out_size, void* d_ws, size_t ws_size,
                              hipStream_t stream) {
    const float* x     = (const float*)d_in[0];  // [m, 32]
    const float* train = (const float*)d_in[1];  // [n, 32]
    const float* resid = (const float*)d_in[2];  // [n]
    const float* sigma = (const float*)d_in[3];  // [m]
    float* out = (float*)d_out;

    int n = in_sizes[2];   // 8192
    int m = in_sizes[3];   // 16384
    int nb = m / 256;      // 64

    // ws layout: fp64 first, then fp32/float2, counter, bf16 records, partials
    double* pS1    = (double*)d_ws;                 // 32*32
    double* pS2    = pS1 + 1024;                    // 32*32
    float2* tr2    = (float2*)(pS2 + 1024);         // n (tnorm, resid)
    float*  qn     = (float*)(tr2 + n);             // m
    float*  rxbuf  = qn + m;                        // m
    float*  bred   = rxbuf + m;                     // 4*nb
    unsigned* counter = (unsigned*)(bred + 4 * nb); // 4 (use [0])
    short*  tb     = (short*)(counter + 4);         // n*64 interleaved hi/lo
    float*  numP   = (float*)(tb + (size_t)n * 64);
    size_t baseBytes = (size_t)((char*)numP - (char*)d_ws);

    // nchunks=32 -> grid (128,32)=4096 blocks = 2 residency passes at 8 blocks/CU
    int nchunks = 32;
    while (nchunks > 1 &&
           baseBytes + (size_t)2 * nchunks * m * sizeof(float) > ws_size)
        nchunks >>= 1;
    float* denP = numP + (size_t)nchunks * m;

    hipMemsetAsync(counter, 0, sizeof(unsigned), stream);

    prep_kernel<<<32 + (m + 255) / 256, 256, 0, stream>>>(x, train, resid, n, m,
                                                          tr2, qn, tb, pS1, pS2);

    dim3 grid_c(m / 128, nchunks);   // 4 waves/block, M=32 per wave
    kde_kernel<<<grid_c, 256, 0, stream>>>(x, tb, tr2, qn, pS1, pS2,
                                           m, n, nchunks, numP, denP);

    reduce_combine<<<nb, 256, 0, stream>>>(numP, denP, sigma, rxbuf, bred,
                                           counter, out, m, nchunks, nb);
}